// Round 14
// baseline (214.394 us; speedup 1.0000x reference)
//
#include <hip/hip_runtime.h>
#include <hip/hip_bf16.h>
#include <hip/hip_fp16.h>

#define N_NODES 10000
#define N_EDGES 100000
#define D 248
#define DP 256      // padded D
#define HDIM 512
#define NNZ 2480
#define LN_EPS 1e-5f
#define PAD_ROWS 128  // row padding so async A-staging overrun stays in our buffers

typedef __attribute__((ext_vector_type(8))) _Float16 f16x8_t;  // 8 f16 = 4 VGPRs
typedef __attribute__((ext_vector_type(4))) float f32x4_t;     // MFMA accum

__device__ __forceinline__ unsigned short f2h(float f) {
  return __builtin_bit_cast(unsigned short, __float2half(f));
}
__device__ __forceinline__ unsigned packh2(float a, float b) {
  return __builtin_bit_cast(unsigned, __floats2half2_rn(a, b));
}
__device__ __forceinline__ void gload_lds16(const unsigned short* gp,
                                            unsigned short* lds_base) {
  __builtin_amdgcn_global_load_lds(
      (const __attribute__((address_space(1))) void*)gp,
      (__attribute__((address_space(3))) void*)lds_base, 16, 0, 0);
}

// ---------------------------------------------------------------------------
// Fused prep: vectorized feature cast (f32->f16), weight casts (f16),
// deg zero, triple CSR by K (packed int2 {J<<16|I, C}) + length-sorted perm.
// ---------------------------------------------------------------------------
#define FEAT_BLOCKS 1250
#define WCAST_BLOCKS (DP + HDIM + DP)
#define ZERO_BLOCKS 40
#define PREP_BLOCKS (FEAT_BLOCKS + WCAST_BLOCKS + ZERO_BLOCKS + 1)

__device__ __forceinline__ void cast_row(const float* src, unsigned short* dst,
                                         int r, int sr, int sc, int dc) {
  for (int c = threadIdx.x; c < dc; c += 256) {
    float v = (r < sr && c < sc) ? src[(size_t)r * sc + c] : 0.f;
    dst[(size_t)r * dc + c] = f2h(v);
  }
}

__global__ __launch_bounds__(256) void prep_kernel(
    const float* __restrict__ features, const float* __restrict__ W_msg,
    const float* __restrict__ W1, const float* __restrict__ W2,
    unsigned short* __restrict__ featH, unsigned short* __restrict__ WmH,
    unsigned short* __restrict__ W1H, unsigned short* __restrict__ W2H,
    int* __restrict__ deg,
    const int* __restrict__ Iv, const int* __restrict__ Jv,
    const int* __restrict__ Kv, const float* __restrict__ Cv,
    int* __restrict__ rsK, int2* __restrict__ trip, int* __restrict__ perm) {
  const int b = blockIdx.x;
  const int tid = threadIdx.x;
  if (b < FEAT_BLOCKS) {
    const int r = b * 8 + (tid >> 5);
    const int c = tid & 31;
    uint4 o = make_uint4(0u, 0u, 0u, 0u);
    if (c < 31) {
      const float* src = features + (size_t)r * D + c * 8;
      float4 v0 = *(const float4*)(src);
      float4 v1 = *(const float4*)(src + 4);
      o.x = packh2(v0.x, v0.y);
      o.y = packh2(v0.z, v0.w);
      o.z = packh2(v1.x, v1.y);
      o.w = packh2(v1.z, v1.w);
    }
    *(uint4*)(featH + (size_t)r * DP + c * 8) = o;
  } else if (b < FEAT_BLOCKS + DP) {
    cast_row(W_msg, WmH, b - FEAT_BLOCKS, D, D, DP);
  } else if (b < FEAT_BLOCKS + DP + HDIM) {
    cast_row(W1, W1H, b - FEAT_BLOCKS - DP, HDIM, D, DP);
  } else if (b < FEAT_BLOCKS + WCAST_BLOCKS) {
    cast_row(W2, W2H, b - FEAT_BLOCKS - DP - HDIM, D, HDIM, HDIM);
  } else if (b < FEAT_BLOCKS + WCAST_BLOCKS + ZERO_BLOCKS) {
    int i = (b - FEAT_BLOCKS - WCAST_BLOCKS) * 256 + tid;
    if (i < N_NODES) deg[i] = 0;
  } else {
    __shared__ int cnt[256];
    __shared__ int off[D];
    cnt[tid] = 0;
    __syncthreads();
    for (int t = tid; t < NNZ; t += 256) atomicAdd(&cnt[Kv[t]], 1);
    __syncthreads();
    if (tid == 0) {
      int run = 0;
      for (int k = 0; k < D; k++) { off[k] = run; rsK[k] = run; run += cnt[k]; }
      rsK[D] = run;
    }
    __syncthreads();
    for (int t = tid; t < NNZ; t += 256) {
      int pos = atomicAdd(&off[Kv[t]], 1);
      trip[pos] = make_int2((Jv[t] << 16) | Iv[t], __float_as_int(Cv[t]));
    }
    // perm: rank all 256 k's by CSR row length descending (ties by index).
    // Balances per-lane loop lengths within bracket waves (divergence fix).
    {
      const int my = cnt[tid];
      int r = 0;
      for (int k2 = 0; k2 < 256; k2++) {
        int c2 = cnt[k2];
        r += (c2 > my) || (c2 == my && k2 < tid);
      }
      perm[r] = tid;
    }
  }
}

// ---------------------------------------------------------------------------
// Edge CSR-by-target (unchanged)
// ---------------------------------------------------------------------------
__global__ __launch_bounds__(256) void hist_tgt(
    const int* __restrict__ ei, int* __restrict__ deg) {
  int e = blockIdx.x * 256 + threadIdx.x;
  if (e < N_EDGES) atomicAdd(&deg[ei[N_EDGES + e]], 1);
}

__global__ __launch_bounds__(256) void scan_deg(
    const int* __restrict__ deg, int2* __restrict__ rs2, int* __restrict__ woff) {
  __shared__ int part[256];
  const int t = threadIdx.x;
  const int base = t * 40;
  int sum = 0;
  for (int i = 0; i < 40; i++) {
    int idx = base + i;
    if (idx < N_NODES) sum += deg[idx];
  }
  part[t] = sum;
  __syncthreads();
  if (t == 0) {
    int run = 0;
    for (int i = 0; i < 256; i++) { int tmp = part[i]; part[i] = run; run += tmp; }
  }
  __syncthreads();
  int run = part[t];
  for (int i = 0; i < 40; i++) {
    int idx = base + i;
    if (idx < N_NODES) {
      int d = deg[idx];
      rs2[idx] = make_int2(run, d);
      woff[idx] = run;
      run += d;
    }
  }
}

__global__ __launch_bounds__(256) void place_edges(
    const int* __restrict__ ei, int* __restrict__ woff, int* __restrict__ esrc) {
  int e = blockIdx.x * 256 + threadIdx.x;
  if (e < N_EDGES) {
    int pos = atomicAdd(&woff[ei[N_EDGES + e]], 1);
    esrc[pos] = ei[e];
  }
}

// ---------------------------------------------------------------------------
// Gather f16 (R13-identical): half-wave per node, packed __half2 accumulation
// ---------------------------------------------------------------------------
__global__ __launch_bounds__(256) void gather_G(
    const unsigned short* __restrict__ FH, const int2* __restrict__ rs2,
    const int* __restrict__ esrc, unsigned short* __restrict__ G) {
  const int tid = threadIdx.x;
  const int lane = tid & 63;
  const int half = lane >> 5;
  const int c = lane & 31;
  const int n = blockIdx.x * 8 + (tid >> 5);  // grid 1250, exact

  const int2 rd = rs2[n];
  const int beg = rd.x, deg = rd.y;
  int eid = (c < deg) ? esrc[beg + c] : 0;

  __half2 a0 = __floats2half2_rn(0.f, 0.f), a1 = a0, a2 = a0, a3 = a0;
  __half2 b0 = a0, b1 = a0, b2 = a0, b3 = a0;
  const unsigned short* FHc = FH + (size_t)c * 8;
  const int dc = (deg < 32) ? deg : 32;
  int j = 0;
  for (; j + 2 <= dc; j += 2) {
    int s0 = __shfl(eid, half * 32 + j);
    int s1 = __shfl(eid, half * 32 + j + 1);
    uint4 u0 = *(const uint4*)(FHc + (size_t)s0 * DP);
    uint4 u1 = *(const uint4*)(FHc + (size_t)s1 * DP);
    a0 = __hadd2(a0, __builtin_bit_cast(__half2, u0.x));
    a1 = __hadd2(a1, __builtin_bit_cast(__half2, u0.y));
    a2 = __hadd2(a2, __builtin_bit_cast(__half2, u0.z));
    a3 = __hadd2(a3, __builtin_bit_cast(__half2, u0.w));
    b0 = __hadd2(b0, __builtin_bit_cast(__half2, u1.x));
    b1 = __hadd2(b1, __builtin_bit_cast(__half2, u1.y));
    b2 = __hadd2(b2, __builtin_bit_cast(__half2, u1.z));
    b3 = __hadd2(b3, __builtin_bit_cast(__half2, u1.w));
  }
  for (; j < deg; j++) {
    int s = (j < 32) ? __shfl(eid, half * 32 + j) : esrc[beg + j];
    uint4 u = *(const uint4*)(FHc + (size_t)s * DP);
    a0 = __hadd2(a0, __builtin_bit_cast(__half2, u.x));
    a1 = __hadd2(a1, __builtin_bit_cast(__half2, u.y));
    a2 = __hadd2(a2, __builtin_bit_cast(__half2, u.z));
    a3 = __hadd2(a3, __builtin_bit_cast(__half2, u.w));
  }
  uint4 o;
  o.x = __builtin_bit_cast(unsigned, __hadd2(a0, b0));
  o.y = __builtin_bit_cast(unsigned, __hadd2(a1, b1));
  o.z = __builtin_bit_cast(unsigned, __hadd2(a2, b2));
  o.w = __builtin_bit_cast(unsigned, __hadd2(a3, b3));
  *(uint4*)(G + (size_t)n * DP + c * 8) = o;
}

// ---------------------------------------------------------------------------
// f16 GEMM-NT via MFMA 16x16x32_f16, async staging (R13-identical).
// EPI: 1 = +bias +silu f16 out; 3 = plain f32 out.
// ---------------------------------------------------------------------------
template <int EPI>
__global__ __launch_bounds__(256) void gemm_f16(
    const unsigned short* __restrict__ A, const unsigned short* __restrict__ B,
    const float* __restrict__ bias, void* __restrict__ Cout,
    int M, int Nn, int K, int lda, int ldb, int ldc) {
  constexpr int BM = 128;
  __shared__ unsigned short As[BM * 64];
  __shared__ unsigned short Bs[64 * 64];
  const int tid = threadIdx.x;
  const int wave = tid >> 6;
  const int lane = tid & 63;
  const int wm = wave >> 1;
  const int wn = wave & 1;
  const int ml = lane & 15;
  const int q = lane >> 4;
  const int m0 = blockIdx.y * BM;
  const int n0 = blockIdx.x * 64;
  const int srow = lane >> 3;
  const int sg = lane & 7;

  f32x4_t acc[4][2];
#pragma unroll
  for (int i = 0; i < 4; i++)
#pragma unroll
    for (int j = 0; j < 2; j++) acc[i][j] = (f32x4_t)0.f;

  for (int k0 = 0; k0 < K; k0 += 64) {
#pragma unroll
    for (int i = 0; i < 4; i++) {
      int t = wave * 4 + i;
      gload_lds16(A + (size_t)(m0 + t * 8 + srow) * lda + k0 + sg * 8, As + t * 512);
    }
#pragma unroll
    for (int i = 0; i < 2; i++) {
      int t = wave * 2 + i;
      gload_lds16(B + (size_t)(n0 + t * 8 + srow) * ldb + k0 + sg * 8, Bs + t * 512);
    }
    __syncthreads();
#pragma unroll
    for (int kk = 0; kk < 2; kk++) {
      f16x8_t a[4], b[2];
#pragma unroll
      for (int im = 0; im < 4; im++) {
        int row = wm * 64 + im * 16 + ml;
        a[im] = *(const f16x8_t*)(As + row * 64 + (kk * 4 + q) * 8);
      }
#pragma unroll
      for (int jn = 0; jn < 2; jn++) {
        int row = wn * 32 + jn * 16 + ml;
        b[jn] = *(const f16x8_t*)(Bs + row * 64 + (kk * 4 + q) * 8);
      }
#pragma unroll
      for (int im = 0; im < 4; im++)
#pragma unroll
        for (int jn = 0; jn < 2; jn++)
          acc[im][jn] = __builtin_amdgcn_mfma_f32_16x16x32_f16(
              a[im], b[jn], acc[im][jn], 0, 0, 0);
    }
    __syncthreads();
  }

#pragma unroll
  for (int im = 0; im < 4; im++) {
#pragma unroll
    for (int jn = 0; jn < 2; jn++) {
      int gn = n0 + wn * 32 + jn * 16 + ml;
#pragma unroll
      for (int reg = 0; reg < 4; reg++) {
        int gm = m0 + wm * 64 + im * 16 + q * 4 + reg;
        if (gm >= M) continue;
        float v = acc[im][jn][reg];
        if (EPI == 1) {
          v += bias[gn];
          v = v / (1.f + __expf(-v));
          ((unsigned short*)Cout)[(size_t)gm * ldc + gn] = f2h(v);
        } else {
          ((float*)Cout)[(size_t)gm * ldc + gn] = v;
        }
      }
    }
  }
}

// ---------------------------------------------------------------------------
// Bracket, packed-f16 2-nodes-per-wave + length-balanced k assignment:
// lane l of chunk kk handles k = perm[kk*64+l] (perm sorted by row length),
// so within-wave loop lengths are similar -> less exec-mask waste.
// Results staged in LDS (perm scatters k), then written coalesced.
// ---------------------------------------------------------------------------
__global__ __launch_bounds__(256) void bracket_kernel(
    const float* __restrict__ S, const unsigned short* __restrict__ FH,
    const int* __restrict__ rsK, const int* __restrict__ perm,
    const int2* __restrict__ trip, unsigned short* __restrict__ agg) {
  __shared__ unsigned sS2[4][DP];
  __shared__ unsigned sF2[4][DP];
  __shared__ unsigned short sOut[4][2 * DP];  // 4 KB
  const int tid = threadIdx.x;
  const int wv = tid >> 6;
  const int lane = tid & 63;
  const int n0 = blockIdx.x * 8 + wv * 2;
  const int n1 = n0 + 1;

  {
    float4 s0 = ((const float4*)(S + (size_t)n0 * DP))[lane];
    float4 s1 = ((const float4*)(S + (size_t)n1 * DP))[lane];
    unsigned* d = &sS2[wv][lane * 4];
    d[0] = packh2(s0.x, s1.x);
    d[1] = packh2(s0.y, s1.y);
    d[2] = packh2(s0.z, s1.z);
    d[3] = packh2(s0.w, s1.w);
  }
  {
    ushort4 u0 = *(const ushort4*)(FH + (size_t)n0 * DP + lane * 4);
    ushort4 u1 = *(const ushort4*)(FH + (size_t)n1 * DP + lane * 4);
    unsigned* d = &sF2[wv][lane * 4];
    d[0] = (unsigned)u0.x | ((unsigned)u1.x << 16);
    d[1] = (unsigned)u0.y | ((unsigned)u1.y << 16);
    d[2] = (unsigned)u0.z | ((unsigned)u1.z << 16);
    d[3] = (unsigned)u0.w | ((unsigned)u1.w << 16);
  }
  __syncthreads();

  const unsigned* S2 = sS2[wv];
  const unsigned* F2 = sF2[wv];
#pragma unroll
  for (int kk = 0; kk < 4; kk++) {
    const int k = perm[kk * 64 + lane];
    float a0 = 0.f, a1 = 0.f, b0 = 0.f, b1 = 0.f;
    if (k < D) {
      const int tb = rsK[k], te = rsK[k + 1];
      int t = tb;
      for (; t + 2 <= te; t += 2) {
        int2 t0 = trip[t], t1 = trip[t + 1];
        __half2 p0 = __hmul2(__builtin_bit_cast(__half2, S2[t0.x & 0xFFFF]),
                             __builtin_bit_cast(__half2, F2[t0.x >> 16]));
        __half2 p1 = __hmul2(__builtin_bit_cast(__half2, S2[t1.x & 0xFFFF]),
                             __builtin_bit_cast(__half2, F2[t1.x >> 16]));
        float2 q0 = __half22float2(p0);
        float2 q1 = __half22float2(p1);
        const float c0 = __int_as_float(t0.y), c1 = __int_as_float(t1.y);
        a0 += c0 * q0.x; a1 += c0 * q0.y;
        b0 += c1 * q1.x; b1 += c1 * q1.y;
      }
      if (t < te) {
        int2 t0 = trip[t];
        __half2 p0 = __hmul2(__builtin_bit_cast(__half2, S2[t0.x & 0xFFFF]),
                             __builtin_bit_cast(__half2, F2[t0.x >> 16]));
        float2 q0 = __half22float2(p0);
        const float c0 = __int_as_float(t0.y);
        a0 += c0 * q0.x; a1 += c0 * q0.y;
      }
    }
    sOut[wv][k] = f2h(a0 + b0);
    sOut[wv][DP + k] = f2h(a1 + b1);
  }
  // same wave wrote a full permutation of k's -> no barrier; coalesced store
  *(ushort4*)(agg + (size_t)n0 * DP + lane * 4) = *(ushort4*)&sOut[wv][lane * 4];
  *(ushort4*)(agg + (size_t)n1 * DP + lane * 4) = *(ushort4*)&sOut[wv][DP + lane * 4];
}

// ---------------------------------------------------------------------------
// Fused GEMM3 + residual + LayerNorm: BM=32, BN=256 (full width), K=512.
// H2 tile lives in LDS; out written directly. 313 blocks, 36 KB LDS.
// ---------------------------------------------------------------------------
__global__ __launch_bounds__(256) void gemm3_ln(
    const unsigned short* __restrict__ H1, const unsigned short* __restrict__ W2H,
    const float* __restrict__ b2, const float* __restrict__ features,
    const float* __restrict__ gamma, const float* __restrict__ beta,
    float* __restrict__ out) {
  __shared__ __align__(16) unsigned char smem[4096 + 32768];
  unsigned short* As = (unsigned short*)smem;          // 32x64 f16 (4 KB)
  unsigned short* Bs = (unsigned short*)(smem + 4096); // 256x64 f16 (32 KB)
  float* H2s = (float*)(smem + 4096);                  // 32x256 f32 overlay

  const int tid = threadIdx.x;
  const int wave = tid >> 6;
  const int lane = tid & 63;
  const int ml = lane & 15;
  const int q = lane >> 4;
  const int srow = lane >> 3;
  const int sg = lane & 7;
  const int m0 = blockIdx.x * 32;

  f32x4_t acc[2][4];
#pragma unroll
  for (int im = 0; im < 2; im++)
#pragma unroll
    for (int jn = 0; jn < 4; jn++) acc[im][jn] = (f32x4_t)0.f;

  for (int ch = 0; ch < 8; ch++) {
    const int k0 = ch * 64;
    // A: 32 rows x 64 cols, 4 insts (1/wave)
    gload_lds16(H1 + (size_t)(m0 + wave * 8 + srow) * HDIM + k0 + sg * 8,
                As + wave * 512);
    // B: 256 rows x 64 cols, 32 insts (8/wave)
#pragma unroll
    for (int i = 0; i < 8; i++) {
      int t = wave * 8 + i;
      gload_lds16(W2H + (size_t)(t * 8 + srow) * HDIM + k0 + sg * 8, Bs + t * 512);
    }
    __syncthreads();
#pragma unroll
    for (int kk = 0; kk < 2; kk++) {
      f16x8_t a[2], b[4];
#pragma unroll
      for (int im = 0; im < 2; im++)
        a[im] = *(const f16x8_t*)(As + (im * 16 + ml) * 64 + (kk * 4 + q) * 8);
#pragma unroll
      for (int jn = 0; jn < 4; jn++)
        b[jn] = *(const f16x8_t*)(Bs + (wave * 64 + jn * 16 + ml) * 64 + (kk * 4 + q) * 8);
#pragma unroll
      for (int im = 0; im < 2; im++)
#pragma unroll
        for (int jn = 0; jn < 4; jn++)
          acc[im][jn] = __builtin_amdgcn_mfma_f32_16x16x32_f16(
              a[im], b[jn], acc[im][jn], 0, 0, 0);
    }
    __syncthreads();
  }

  // epilogue -> H2s (overlays Bs; all Bs reads complete after last barrier)
#pragma unroll
  for (int im = 0; im < 2; im++) {
#pragma unroll
    for (int jn = 0; jn < 4; jn++) {
      const int gn = wave * 64 + jn * 16 + ml;
      const float bb = (gn < D) ? b2[gn] : 0.f;
#pragma unroll
      for (int reg = 0; reg < 4; reg++)
        H2s[(im * 16 + q * 4 + reg) * 256 + gn] = acc[im][jn][reg] + bb;
    }
  }
  __syncthreads();

  // residual + LN: 8 rows per wave, butterfly shfl
  for (int i = 0; i < 8; i++) {
    const int r = wave * 8 + i;
    const int n = m0 + r;
    if (n >= N_NODES) continue;  // wave-uniform
    float4 x = make_float4(0.f, 0.f, 0.f, 0.f);
    if (lane < 62) {
      float4 f = *(const float4*)(features + (size_t)n * D + lane * 4);
      float4 h = *(const float4*)(H2s + r * 256 + lane * 4);
      x = make_float4(f.x + h.x, f.y + h.y, f.z + h.z, f.w + h.w);
    }
    float s = x.x + x.y + x.z + x.w;
#pragma unroll
    for (int o = 32; o > 0; o >>= 1) s += __shfl_xor(s, o);
    const float mu = s * (1.f / (float)D);
    float4 xc = make_float4(x.x - mu, x.y - mu, x.z - mu, x.w - mu);
    float vv = 0.f;
    if (lane < 62) vv = xc.x * xc.x + xc.y * xc.y + xc.z * xc.z + xc.w * xc.w;
#pragma unroll
    for (int o = 32; o > 0; o >>= 1) vv += __shfl_xor(vv, o);
    const float rstd = rsqrtf(vv * (1.f / (float)D) + LN_EPS);
    if (lane < 62) {
      float4 g = *(const float4*)(gamma + lane * 4);
      float4 b = *(const float4*)(beta + lane * 4);
      float4 o;
      o.x = xc.x * rstd * g.x + b.x;
      o.y = xc.y * rstd * g.y + b.y;
      o.z = xc.z * rstd * g.z + b.z;
      o.w = xc.w * rstd * g.w + b.w;
      *(float4*)(out + (size_t)n * D + lane * 4) = o;
    }
  }
}

// ---------------------------------------------------------------------------
extern "C" void kernel_launch(void* const* d_in, const int* in_sizes, int n_in,
                              void* d_out, int out_size, void* d_ws, size_t ws_size,
                              hipStream_t stream) {
  const float* features = (const float*)d_in[0];
  const int*   ei       = (const int*)d_in[1];
  const float* W_msg    = (const float*)d_in[2];
  const float* W1       = (const float*)d_in[3];
  const float* b1       = (const float*)d_in[4];
  const float* W2       = (const float*)d_in[5];
  const float* b2       = (const float*)d_in[6];
  const float* gamma    = (const float*)d_in[7];
  const float* beta     = (const float*)d_in[8];
  const int*   Iv       = (const int*)d_in[9];
  const int*   Jv       = (const int*)d_in[10];
  const int*   Kv       = (const int*)d_in[11];
  const float* Cv       = (const float*)d_in[12];
  float* out = (float*)d_out;

  char* cur = (char*)d_ws;
  auto alloc = [&](size_t bytes) {
    char* p = cur;
    cur += (bytes + 255) & ~(size_t)255;
    return p;
  };
  const size_t NP = (size_t)N_NODES + PAD_ROWS;
  unsigned short* featH = (unsigned short*)alloc(NP * DP * 2);
  unsigned short* WmH   = (unsigned short*)alloc((size_t)DP * DP * 2);
  unsigned short* W1H   = (unsigned short*)alloc((size_t)HDIM * DP * 2);
  unsigned short* W2H   = (unsigned short*)alloc((size_t)DP * HDIM * 2);
  unsigned short* G     = (unsigned short*)alloc(NP * DP * 2);
  float*          S     = (float*)alloc((size_t)N_NODES * DP * 4);
  unsigned short* aggH  = (unsigned short*)alloc(NP * DP * 2);
  unsigned short* H1H   = (unsigned short*)alloc(NP * HDIM * 2);
  int*  rsK  = (int*)alloc((D + 1) * 4);
  int*  perm = (int*)alloc(256 * 4);
  int2* trip = (int2*)alloc(NNZ * 8);
  int*  deg  = (int*)alloc(N_NODES * 4);
  int2* rs2  = (int2*)alloc((size_t)N_NODES * 8);
  int*  woff = (int*)alloc(N_NODES * 4);
  int*  esrc = (int*)alloc(N_EDGES * 4);

  dim3 blk(256);

  // 1) prep
  prep_kernel<<<PREP_BLOCKS, blk, 0, stream>>>(
      features, W_msg, W1, W2, featH, WmH, W1H, W2H, deg,
      Iv, Jv, Kv, Cv, rsK, trip, perm);
  // 2) edge CSR by target
  hist_tgt<<<(N_EDGES + 255) / 256, blk, 0, stream>>>(ei, deg);
  scan_deg<<<1, blk, 0, stream>>>(deg, rs2, woff);
  place_edges<<<(N_EDGES + 255) / 256, blk, 0, stream>>>(ei, woff, esrc);
  // 3) gather
  gather_G<<<N_NODES / 8, blk, 0, stream>>>(featH, rs2, esrc, G);
  // 4) S = G @ Wm^T  (f32 out)
  gemm_f16<3><<<dim3(DP / 64, (N_NODES + 127) / 128), blk, 0, stream>>>(
      G, WmH, nullptr, S, N_NODES, DP, DP, DP, DP, DP);
  // 5) agg = bracket(S, featH)  -- perm-balanced
  bracket_kernel<<<N_NODES / 8, blk, 0, stream>>>(S, featH, rsK, perm, trip, aggH);
  // 6) H1 = silu(agg @ W1^T + b1)
  gemm_f16<1><<<dim3(HDIM / 64, (N_NODES + 127) / 128), blk, 0, stream>>>(
      aggH, W1H, b1, H1H, N_NODES, HDIM, DP, DP, DP, HDIM);
  // 7) out = LN(features + H1 @ W2^T + b2)   (fused GEMM3+LN)
  gemm3_ln<<<(N_NODES + 31) / 32, blk, 0, stream>>>(
      H1H, W2H, b2, features, gamma, beta, out);
}

// Round 15
// 212.785 us; speedup vs baseline: 1.0076x; 1.0076x over previous
//
#include <hip/hip_runtime.h>
#include <hip/hip_bf16.h>
#include <hip/hip_fp16.h>

#define N_NODES 10000
#define N_EDGES 100000
#define D 248
#define DP 256      // padded D
#define HDIM 512
#define NNZ 2480
#define LN_EPS 1e-5f
#define PAD_ROWS 128  // row padding so async A-staging overrun stays in our buffers

typedef __attribute__((ext_vector_type(8))) _Float16 f16x8_t;  // 8 f16 = 4 VGPRs
typedef __attribute__((ext_vector_type(4))) float f32x4_t;     // MFMA accum

__device__ __forceinline__ unsigned short f2h(float f) {
  return __builtin_bit_cast(unsigned short, __float2half(f));
}
__device__ __forceinline__ unsigned packh2(float a, float b) {
  return __builtin_bit_cast(unsigned, __floats2half2_rn(a, b));
}
__device__ __forceinline__ void gload_lds16(const unsigned short* gp,
                                            unsigned short* lds_base) {
  __builtin_amdgcn_global_load_lds(
      (const __attribute__((address_space(1))) void*)gp,
      (__attribute__((address_space(3))) void*)lds_base, 16, 0, 0);
}

// ---------------------------------------------------------------------------
// Fused prep (R13-identical): vectorized feature cast (f32->f16), weight
// casts (f16), deg zero, triple CSR by K (packed int2 {J<<16|I, C}).
// ---------------------------------------------------------------------------
#define FEAT_BLOCKS 1250
#define WCAST_BLOCKS (DP + HDIM + DP)
#define ZERO_BLOCKS 40
#define PREP_BLOCKS (FEAT_BLOCKS + WCAST_BLOCKS + ZERO_BLOCKS + 1)

__device__ __forceinline__ void cast_row(const float* src, unsigned short* dst,
                                         int r, int sr, int sc, int dc) {
  for (int c = threadIdx.x; c < dc; c += 256) {
    float v = (r < sr && c < sc) ? src[(size_t)r * sc + c] : 0.f;
    dst[(size_t)r * dc + c] = f2h(v);
  }
}

__global__ __launch_bounds__(256) void prep_kernel(
    const float* __restrict__ features, const float* __restrict__ W_msg,
    const float* __restrict__ W1, const float* __restrict__ W2,
    unsigned short* __restrict__ featH, unsigned short* __restrict__ WmH,
    unsigned short* __restrict__ W1H, unsigned short* __restrict__ W2H,
    int* __restrict__ deg,
    const int* __restrict__ Iv, const int* __restrict__ Jv,
    const int* __restrict__ Kv, const float* __restrict__ Cv,
    int* __restrict__ rsK, int2* __restrict__ trip) {
  const int b = blockIdx.x;
  const int tid = threadIdx.x;
  if (b < FEAT_BLOCKS) {
    const int r = b * 8 + (tid >> 5);
    const int c = tid & 31;
    uint4 o = make_uint4(0u, 0u, 0u, 0u);
    if (c < 31) {
      const float* src = features + (size_t)r * D + c * 8;
      float4 v0 = *(const float4*)(src);
      float4 v1 = *(const float4*)(src + 4);
      o.x = packh2(v0.x, v0.y);
      o.y = packh2(v0.z, v0.w);
      o.z = packh2(v1.x, v1.y);
      o.w = packh2(v1.z, v1.w);
    }
    *(uint4*)(featH + (size_t)r * DP + c * 8) = o;
  } else if (b < FEAT_BLOCKS + DP) {
    cast_row(W_msg, WmH, b - FEAT_BLOCKS, D, D, DP);
  } else if (b < FEAT_BLOCKS + DP + HDIM) {
    cast_row(W1, W1H, b - FEAT_BLOCKS - DP, HDIM, D, DP);
  } else if (b < FEAT_BLOCKS + WCAST_BLOCKS) {
    cast_row(W2, W2H, b - FEAT_BLOCKS - DP - HDIM, D, HDIM, HDIM);
  } else if (b < FEAT_BLOCKS + WCAST_BLOCKS + ZERO_BLOCKS) {
    int i = (b - FEAT_BLOCKS - WCAST_BLOCKS) * 256 + tid;
    if (i < N_NODES) deg[i] = 0;
  } else {
    __shared__ int cnt[D];
    __shared__ int off[D];
    for (int k = tid; k < D; k += 256) cnt[k] = 0;
    __syncthreads();
    for (int t = tid; t < NNZ; t += 256) atomicAdd(&cnt[Kv[t]], 1);
    __syncthreads();
    if (tid == 0) {
      int run = 0;
      for (int k = 0; k < D; k++) { off[k] = run; rsK[k] = run; run += cnt[k]; }
      rsK[D] = run;
    }
    __syncthreads();
    for (int t = tid; t < NNZ; t += 256) {
      int pos = atomicAdd(&off[Kv[t]], 1);
      trip[pos] = make_int2((Jv[t] << 16) | Iv[t], __float_as_int(Cv[t]));
    }
  }
}

// ---------------------------------------------------------------------------
// Edge CSR-by-target (R13-identical)
// ---------------------------------------------------------------------------
__global__ __launch_bounds__(256) void hist_tgt(
    const int* __restrict__ ei, int* __restrict__ deg) {
  int e = blockIdx.x * 256 + threadIdx.x;
  if (e < N_EDGES) atomicAdd(&deg[ei[N_EDGES + e]], 1);
}

__global__ __launch_bounds__(256) void scan_deg(
    const int* __restrict__ deg, int2* __restrict__ rs2, int* __restrict__ woff) {
  __shared__ int part[256];
  const int t = threadIdx.x;
  const int base = t * 40;
  int sum = 0;
  for (int i = 0; i < 40; i++) {
    int idx = base + i;
    if (idx < N_NODES) sum += deg[idx];
  }
  part[t] = sum;
  __syncthreads();
  if (t == 0) {
    int run = 0;
    for (int i = 0; i < 256; i++) { int tmp = part[i]; part[i] = run; run += tmp; }
  }
  __syncthreads();
  int run = part[t];
  for (int i = 0; i < 40; i++) {
    int idx = base + i;
    if (idx < N_NODES) {
      int d = deg[idx];
      rs2[idx] = make_int2(run, d);
      woff[idx] = run;
      run += d;
    }
  }
}

__global__ __launch_bounds__(256) void place_edges(
    const int* __restrict__ ei, int* __restrict__ woff, int* __restrict__ esrc) {
  int e = blockIdx.x * 256 + threadIdx.x;
  if (e < N_EDGES) {
    int pos = atomicAdd(&woff[ei[N_EDGES + e]], 1);
    esrc[pos] = ei[e];
  }
}

// ---------------------------------------------------------------------------
// Gather f16 (R13-identical): half-wave per node, packed __half2 accumulation
// ---------------------------------------------------------------------------
__global__ __launch_bounds__(256) void gather_G(
    const unsigned short* __restrict__ FH, const int2* __restrict__ rs2,
    const int* __restrict__ esrc, unsigned short* __restrict__ G) {
  const int tid = threadIdx.x;
  const int lane = tid & 63;
  const int half = lane >> 5;
  const int c = lane & 31;
  const int n = blockIdx.x * 8 + (tid >> 5);  // grid 1250, exact

  const int2 rd = rs2[n];
  const int beg = rd.x, deg = rd.y;
  int eid = (c < deg) ? esrc[beg + c] : 0;

  __half2 a0 = __floats2half2_rn(0.f, 0.f), a1 = a0, a2 = a0, a3 = a0;
  __half2 b0 = a0, b1 = a0, b2 = a0, b3 = a0;
  const unsigned short* FHc = FH + (size_t)c * 8;
  const int dc = (deg < 32) ? deg : 32;
  int j = 0;
  for (; j + 2 <= dc; j += 2) {
    int s0 = __shfl(eid, half * 32 + j);
    int s1 = __shfl(eid, half * 32 + j + 1);
    uint4 u0 = *(const uint4*)(FHc + (size_t)s0 * DP);
    uint4 u1 = *(const uint4*)(FHc + (size_t)s1 * DP);
    a0 = __hadd2(a0, __builtin_bit_cast(__half2, u0.x));
    a1 = __hadd2(a1, __builtin_bit_cast(__half2, u0.y));
    a2 = __hadd2(a2, __builtin_bit_cast(__half2, u0.z));
    a3 = __hadd2(a3, __builtin_bit_cast(__half2, u0.w));
    b0 = __hadd2(b0, __builtin_bit_cast(__half2, u1.x));
    b1 = __hadd2(b1, __builtin_bit_cast(__half2, u1.y));
    b2 = __hadd2(b2, __builtin_bit_cast(__half2, u1.z));
    b3 = __hadd2(b3, __builtin_bit_cast(__half2, u1.w));
  }
  for (; j < deg; j++) {
    int s = (j < 32) ? __shfl(eid, half * 32 + j) : esrc[beg + j];
    uint4 u = *(const uint4*)(FHc + (size_t)s * DP);
    a0 = __hadd2(a0, __builtin_bit_cast(__half2, u.x));
    a1 = __hadd2(a1, __builtin_bit_cast(__half2, u.y));
    a2 = __hadd2(a2, __builtin_bit_cast(__half2, u.z));
    a3 = __hadd2(a3, __builtin_bit_cast(__half2, u.w));
  }
  uint4 o;
  o.x = __builtin_bit_cast(unsigned, __hadd2(a0, b0));
  o.y = __builtin_bit_cast(unsigned, __hadd2(a1, b1));
  o.z = __builtin_bit_cast(unsigned, __hadd2(a2, b2));
  o.w = __builtin_bit_cast(unsigned, __hadd2(a3, b3));
  *(uint4*)(G + (size_t)n * DP + c * 8) = o;  // c=31 stays zero (featH pad=0)
}

// ---------------------------------------------------------------------------
// f16 GEMM-NT via MFMA 16x16x32_f16, async global_load_lds staging.
// EPI: 0 = plain f16 out; 1 = +bias +silu f16 out; 2 = +bias(n<D) f32 out.
// ---------------------------------------------------------------------------
template <int EPI>
__global__ __launch_bounds__(256) void gemm_f16(
    const unsigned short* __restrict__ A, const unsigned short* __restrict__ B,
    const float* __restrict__ bias, void* __restrict__ Cout,
    int M, int Nn, int K, int lda, int ldb, int ldc) {
  constexpr int BM = 128;
  __shared__ unsigned short As[BM * 64];
  __shared__ unsigned short Bs[64 * 64];
  const int tid = threadIdx.x;
  const int wave = tid >> 6;
  const int lane = tid & 63;
  const int wm = wave >> 1;
  const int wn = wave & 1;
  const int ml = lane & 15;
  const int q = lane >> 4;
  const int m0 = blockIdx.y * BM;
  const int n0 = blockIdx.x * 64;
  const int srow = lane >> 3;
  const int sg = lane & 7;

  f32x4_t acc[4][2];
#pragma unroll
  for (int i = 0; i < 4; i++)
#pragma unroll
    for (int j = 0; j < 2; j++) acc[i][j] = (f32x4_t)0.f;

  for (int k0 = 0; k0 < K; k0 += 64) {
#pragma unroll
    for (int i = 0; i < 4; i++) {
      int t = wave * 4 + i;
      gload_lds16(A + (size_t)(m0 + t * 8 + srow) * lda + k0 + sg * 8, As + t * 512);
    }
#pragma unroll
    for (int i = 0; i < 2; i++) {
      int t = wave * 2 + i;
      gload_lds16(B + (size_t)(n0 + t * 8 + srow) * ldb + k0 + sg * 8, Bs + t * 512);
    }
    __syncthreads();
#pragma unroll
    for (int kk = 0; kk < 2; kk++) {
      f16x8_t a[4], b[2];
#pragma unroll
      for (int im = 0; im < 4; im++) {
        int row = wm * 64 + im * 16 + ml;
        a[im] = *(const f16x8_t*)(As + row * 64 + (kk * 4 + q) * 8);
      }
#pragma unroll
      for (int jn = 0; jn < 2; jn++) {
        int row = wn * 32 + jn * 16 + ml;
        b[jn] = *(const f16x8_t*)(Bs + row * 64 + (kk * 4 + q) * 8);
      }
#pragma unroll
      for (int im = 0; im < 4; im++)
#pragma unroll
        for (int jn = 0; jn < 2; jn++)
          acc[im][jn] = __builtin_amdgcn_mfma_f32_16x16x32_f16(
              a[im], b[jn], acc[im][jn], 0, 0, 0);
    }
    __syncthreads();
  }

  // D[m][n]: n = lane&15, m = quad*4 + reg  [C/D layout dtype-independent]
#pragma unroll
  for (int im = 0; im < 4; im++) {
#pragma unroll
    for (int jn = 0; jn < 2; jn++) {
      int gn = n0 + wn * 32 + jn * 16 + ml;
#pragma unroll
      for (int reg = 0; reg < 4; reg++) {
        int gm = m0 + wm * 64 + im * 16 + q * 4 + reg;
        if (gm >= M) continue;
        float v = acc[im][jn][reg];
        if (EPI == 0) {
          ((unsigned short*)Cout)[(size_t)gm * ldc + gn] = f2h(v);
        } else if (EPI == 1) {
          v += bias[gn];
          v = v / (1.f + __expf(-v));
          ((unsigned short*)Cout)[(size_t)gm * ldc + gn] = f2h(v);
        } else {
          v += (gn < D) ? bias[gn] : 0.f;
          ((float*)Cout)[(size_t)gm * ldc + gn] = v;
        }
      }
    }
  }
}

// ---------------------------------------------------------------------------
// Bracket, packed-f16 2-nodes-per-wave (R13 core, S now f16 from GEMM1):
// both S and F pairs staged by OR-pack (no cvt). Accumulation f32.
// ---------------------------------------------------------------------------
__global__ __launch_bounds__(256) void bracket_kernel(
    const unsigned short* __restrict__ SH, const unsigned short* __restrict__ FH,
    const int* __restrict__ rsK, const int2* __restrict__ trip,
    unsigned short* __restrict__ agg) {
  __shared__ unsigned sS2[4][DP];  // half2-packed node pair
  __shared__ unsigned sF2[4][DP];
  const int tid = threadIdx.x;
  const int wv = tid >> 6;
  const int lane = tid & 63;
  const int n0 = blockIdx.x * 8 + wv * 2;
  const int n1 = n0 + 1;

  {
    ushort4 u0 = *(const ushort4*)(SH + (size_t)n0 * DP + lane * 4);
    ushort4 u1 = *(const ushort4*)(SH + (size_t)n1 * DP + lane * 4);
    unsigned* d = &sS2[wv][lane * 4];
    d[0] = (unsigned)u0.x | ((unsigned)u1.x << 16);
    d[1] = (unsigned)u0.y | ((unsigned)u1.y << 16);
    d[2] = (unsigned)u0.z | ((unsigned)u1.z << 16);
    d[3] = (unsigned)u0.w | ((unsigned)u1.w << 16);
  }
  {
    ushort4 u0 = *(const ushort4*)(FH + (size_t)n0 * DP + lane * 4);
    ushort4 u1 = *(const ushort4*)(FH + (size_t)n1 * DP + lane * 4);
    unsigned* d = &sF2[wv][lane * 4];
    d[0] = (unsigned)u0.x | ((unsigned)u1.x << 16);
    d[1] = (unsigned)u0.y | ((unsigned)u1.y << 16);
    d[2] = (unsigned)u0.z | ((unsigned)u1.z << 16);
    d[3] = (unsigned)u0.w | ((unsigned)u1.w << 16);
  }
  __syncthreads();

  const unsigned* S2 = sS2[wv];
  const unsigned* F2 = sF2[wv];
#pragma unroll
  for (int kk = 0; kk < 4; kk++) {
    const int k = lane + kk * 64;
    float a0 = 0.f, a1 = 0.f, b0 = 0.f, b1 = 0.f;
    if (k < D) {
      const int tb = rsK[k], te = rsK[k + 1];
      int t = tb;
      for (; t + 2 <= te; t += 2) {
        int2 t0 = trip[t], t1 = trip[t + 1];
        __half2 p0 = __hmul2(__builtin_bit_cast(__half2, S2[t0.x & 0xFFFF]),
                             __builtin_bit_cast(__half2, F2[t0.x >> 16]));
        __half2 p1 = __hmul2(__builtin_bit_cast(__half2, S2[t1.x & 0xFFFF]),
                             __builtin_bit_cast(__half2, F2[t1.x >> 16]));
        float2 q0 = __half22float2(p0);
        float2 q1 = __half22float2(p1);
        const float c0 = __int_as_float(t0.y), c1 = __int_as_float(t1.y);
        a0 += c0 * q0.x; a1 += c0 * q0.y;
        b0 += c1 * q1.x; b1 += c1 * q1.y;
      }
      if (t < te) {
        int2 t0 = trip[t];
        __half2 p0 = __hmul2(__builtin_bit_cast(__half2, S2[t0.x & 0xFFFF]),
                             __builtin_bit_cast(__half2, F2[t0.x >> 16]));
        float2 q0 = __half22float2(p0);
        const float c0 = __int_as_float(t0.y);
        a0 += c0 * q0.x; a1 += c0 * q0.y;
      }
    }
    agg[(size_t)n0 * DP + k] = f2h(a0 + b0);  // k>=D -> 0 pad
    agg[(size_t)n1 * DP + k] = f2h(a1 + b1);
  }
}

// ---------------------------------------------------------------------------
// Residual + LayerNorm, wave-per-node (R13-identical)
// ---------------------------------------------------------------------------
__global__ __launch_bounds__(256) void ln_kernel(
    const float* __restrict__ x0, const float* __restrict__ h2,
    const float* __restrict__ gamma, const float* __restrict__ beta,
    float* __restrict__ out) {
  const int tid = threadIdx.x;
  const int wv = tid >> 6;
  const int lane = tid & 63;
  const int n = blockIdx.x * 4 + wv;

  float4 x = make_float4(0.f, 0.f, 0.f, 0.f);
  if (lane < 62) {
    float4 f = *(const float4*)(x0 + (size_t)n * D + lane * 4);
    float4 h = *(const float4*)(h2 + (size_t)n * DP + lane * 4);
    x = make_float4(f.x + h.x, f.y + h.y, f.z + h.z, f.w + h.w);
  }
  float s = x.x + x.y + x.z + x.w;
#pragma unroll
  for (int o = 32; o > 0; o >>= 1) s += __shfl_xor(s, o);
  const float mu = s * (1.f / (float)D);
  float4 xc = make_float4(x.x - mu, x.y - mu, x.z - mu, x.w - mu);
  float v = 0.f;
  if (lane < 62) v = xc.x * xc.x + xc.y * xc.y + xc.z * xc.z + xc.w * xc.w;
#pragma unroll
  for (int o = 32; o > 0; o >>= 1) v += __shfl_xor(v, o);
  const float rstd = rsqrtf(v * (1.f / (float)D) + LN_EPS);
  if (lane < 62) {
    float4 g = *(const float4*)(gamma + lane * 4);
    float4 b = *(const float4*)(beta + lane * 4);
    float4 o;
    o.x = xc.x * rstd * g.x + b.x;
    o.y = xc.y * rstd * g.y + b.y;
    o.z = xc.z * rstd * g.z + b.z;
    o.w = xc.w * rstd * g.w + b.w;
    *(float4*)(out + (size_t)n * D + lane * 4) = o;
  }
}

// ---------------------------------------------------------------------------
extern "C" void kernel_launch(void* const* d_in, const int* in_sizes, int n_in,
                              void* d_out, int out_size, void* d_ws, size_t ws_size,
                              hipStream_t stream) {
  const float* features = (const float*)d_in[0];
  const int*   ei       = (const int*)d_in[1];
  const float* W_msg    = (const float*)d_in[2];
  const float* W1       = (const float*)d_in[3];
  const float* b1       = (const float*)d_in[4];
  const float* W2       = (const float*)d_in[5];
  const float* b2       = (const float*)d_in[6];
  const float* gamma    = (const float*)d_in[7];
  const float* beta     = (const float*)d_in[8];
  const int*   Iv       = (const int*)d_in[9];
  const int*   Jv       = (const int*)d_in[10];
  const int*   Kv       = (const int*)d_in[11];
  const float* Cv       = (const float*)d_in[12];
  float* out = (float*)d_out;

  char* cur = (char*)d_ws;
  auto alloc = [&](size_t bytes) {
    char* p = cur;
    cur += (bytes + 255) & ~(size_t)255;
    return p;
  };
  const size_t NP = (size_t)N_NODES + PAD_ROWS;
  unsigned short* featH = (unsigned short*)alloc(NP * DP * 2);
  unsigned short* WmH   = (unsigned short*)alloc((size_t)DP * DP * 2);
  unsigned short* W1H   = (unsigned short*)alloc((size_t)HDIM * DP * 2);
  unsigned short* W2H   = (unsigned short*)alloc((size_t)DP * HDIM * 2);
  unsigned short* G     = (unsigned short*)alloc(NP * DP * 2);
  unsigned short* S16   = (unsigned short*)alloc(NP * DP * 2);   // f16 S
  unsigned short* aggH  = (unsigned short*)alloc(NP * DP * 2);
  unsigned short* H1H   = (unsigned short*)alloc(NP * HDIM * 2);
  float*          H2    = (float*)alloc((size_t)N_NODES * DP * 4);
  int*  rsK  = (int*)alloc((D + 1) * 4);
  int2* trip = (int2*)alloc(NNZ * 8);
  int*  deg  = (int*)alloc(N_NODES * 4);
  int2* rs2  = (int2*)alloc((size_t)N_NODES * 8);
  int*  woff = (int*)alloc(N_NODES * 4);
  int*  esrc = (int*)alloc(N_EDGES * 4);

  dim3 blk(256);

  // 1) prep
  prep_kernel<<<PREP_BLOCKS, blk, 0, stream>>>(
      features, W_msg, W1, W2, featH, WmH, W1H, W2H, deg,
      Iv, Jv, Kv, Cv, rsK, trip);
  // 2) edge CSR by target
  hist_tgt<<<(N_EDGES + 255) / 256, blk, 0, stream>>>(ei, deg);
  scan_deg<<<1, blk, 0, stream>>>(deg, rs2, woff);
  place_edges<<<(N_EDGES + 255) / 256, blk, 0, stream>>>(ei, woff, esrc);
  // 3) gather: half-wave per node, packed-f16 accumulation
  gather_G<<<N_NODES / 8, blk, 0, stream>>>(featH, rs2, esrc, G);
  // 4) S = G @ Wm^T  (f16 out -- same rounding point the bracket already used)
  gemm_f16<0><<<dim3(DP / 64, (N_NODES + 127) / 128), blk, 0, stream>>>(
      G, WmH, nullptr, S16, N_NODES, DP, DP, DP, DP, DP);
  // 5) agg = bracket(S16, featH)  -- packed-f16 node pairs
  bracket_kernel<<<N_NODES / 8, blk, 0, stream>>>(S16, featH, rsK, trip, aggH);
  // 6) H1 = silu(agg @ W1^T + b1)
  gemm_f16<1><<<dim3(HDIM / 64, (N_NODES + 127) / 128), blk, 0, stream>>>(
      aggH, W1H, b1, H1H, N_NODES, HDIM, DP, DP, DP, HDIM);
  // 7) H2 = H1 @ W2^T + b2  (f32 out)
  gemm_f16<2><<<dim3(DP / 64, (N_NODES + 127) / 128), blk, 0, stream>>>(
      H1H, W2H, b2, H2, N_NODES, DP, HDIM, HDIM, HDIM, DP);
  // 8) out = LN(features + H2)
  ln_kernel<<<N_NODES / 4, blk, 0, stream>>>(features, H2, gamma, beta, out);
}